// Round 16
// baseline (588.246 us; speedup 1.0000x reference)
//
#include <hip/hip_runtime.h>
#include <hip/hip_bf16.h>

// Problem constants (fixed by the reference)
#define B_ 1024
#define L_ 32
#define M_ 128
#define N_ 4096
#define S_ 32
#define ROWS (B_ * L_)          // 32768 rows of length N_

typedef __attribute__((ext_vector_type(8))) short    short8_t;   // 8 bf16 (4 VGPR)
typedef __attribute__((ext_vector_type(8))) unsigned short ushort8_t;
typedef __attribute__((ext_vector_type(4))) float    f32x4;

__device__ __forceinline__ unsigned short f2bf(float x) {  // RNE bf16
    unsigned u = __float_as_uint(x);
    unsigned r = (u + 0x7FFFu + ((u >> 16) & 1u)) >> 16;
    return (unsigned short)r;
}
__device__ __forceinline__ float bf2f(unsigned short h) {
    return __uint_as_float((unsigned)h << 16);
}

// ---------------------------------------------------------------------------
// P0: PROLOGUE mega-kernel (block-range dispatch over independent jobs):
//   [0,2048)        zero LOW 8KB half of every y row (streaming writes)
//   [2048,10240)    prep_w: Wbf = bf16(We), cvec = b_d . We_n
//   [10240,26624)   prep_a: Abf = bf16(kin), layout [l][b][128]
//   [26624,26624+nT) transpose Wd -> WdT (only when WdT does NOT alias Wbf,
//                    i.e. ws_size large enough; else nT=0 and transpose runs
//                    as a separate kernel after the encoder)
// Fusing lets the write-bound zero co-execute with the read-heavy preps.
// ---------------------------------------------------------------------------
__global__ __launch_bounds__(256) void prologue(float* __restrict__ y,
                                                const float* __restrict__ We,
                                                const float* __restrict__ bd,
                                                unsigned short* __restrict__ Wbf,
                                                float* __restrict__ cvec,
                                                const float* __restrict__ kin,
                                                unsigned short* __restrict__ Abf,
                                                const float* __restrict__ Wd,
                                                float* __restrict__ WdT) {
    __shared__ float t[32][33];
    const int bid = blockIdx.x;
    const int tid = threadIdx.x;

    if (bid < 2048) {
        // zero low halves of y
        const float4 z = {0.f, 0.f, 0.f, 0.f};
        int idx = bid * 256 + tid;
        for (int i = idx; i < ROWS * 512; i += 2048 * 256) {
            int row = i >> 9, slot = i & 511;
            reinterpret_cast<float4*>(y + (size_t)row * N_)[slot] = z;
        }
    } else if (bid < 10240) {
        // prep_w + bias_dot
        int wb = bid - 2048;
        int l = wb >> 8, nb = wb & 255;
        int nl = tid >> 4, tt = tid & 15;
        int n = nb * 16 + nl;
        const float* w = We + ((size_t)l * N_ + n) * M_ + tt * 8;
        const float* b = bd + l * M_ + tt * 8;
        float4 w0 = *(const float4*)(w), w1 = *(const float4*)(w + 4);
        float4 b0 = *(const float4*)(b), b1 = *(const float4*)(b + 4);
        ushort8_t o;
        o[0] = f2bf(w0.x); o[1] = f2bf(w0.y); o[2] = f2bf(w0.z); o[3] = f2bf(w0.w);
        o[4] = f2bf(w1.x); o[5] = f2bf(w1.y); o[6] = f2bf(w1.z); o[7] = f2bf(w1.w);
        *reinterpret_cast<ushort8_t*>(Wbf + ((size_t)l * N_ + n) * 128 + tt * 8) = o;
        float s = w0.x*b0.x + w0.y*b0.y + w0.z*b0.z + w0.w*b0.w
                + w1.x*b1.x + w1.y*b1.y + w1.z*b1.z + w1.w*b1.w;
        #pragma unroll
        for (int oo = 8; oo > 0; oo >>= 1) s += __shfl_xor(s, oo, 64);
        if (tt == 0) cvec[(size_t)l * N_ + n] = s;
    } else if (bid < 26624) {
        // prep_a
        int g = (bid - 10240) * 256 + tid;        // over B*L*M
        int b = g >> 12, l = (g >> 7) & 31, m = g & 127;
        Abf[(((size_t)l * B_ + b) << 7) + m] = f2bf(kin[g]);
    } else {
        // transpose Wd -> WdT (non-aliased WdT only)
        int tb = bid - 26624;
        int l  = tb >> 9;
        int rem = tb & 511;
        int n0 = (rem & 127) * 32, m0 = (rem >> 7) * 32;
        int tx = tid & 31, ty = tid >> 5;
        const float* src = Wd + (size_t)l * M_ * N_;
        for (int i = ty; i < 32; i += 8)
            t[i][tx] = src[(size_t)(m0 + i) * N_ + n0 + tx];
        __syncthreads();
        float* dst = WdT + (size_t)l * N_ * M_;
        for (int i = ty; i < 32; i += 8)
            dst[(size_t)(n0 + i) * M_ + m0 + tx] = t[tx][i];
    }
}

// ---------------------------------------------------------------------------
// K0: standalone transpose (fallback when WdT aliases Wbf: must run AFTER
// the encoder finishes reading Wbf)
// ---------------------------------------------------------------------------
__global__ __launch_bounds__(256) void transpose_wd(const float* __restrict__ Wd,
                                                    float* __restrict__ WdT) {
    __shared__ float t[32][33];
    int l = blockIdx.z;
    int n0 = blockIdx.x * 32, m0 = blockIdx.y * 32;
    int tx = threadIdx.x & 31, ty = threadIdx.x >> 5;
    const float* src = Wd + (size_t)l * M_ * N_;
    for (int i = ty; i < 32; i += 8)
        t[i][tx] = src[(size_t)(m0 + i) * N_ + n0 + tx];
    __syncthreads();
    float* dst = WdT + (size_t)l * N_ * M_;
    for (int i = ty; i < 32; i += 8)
        dst[(size_t)(n0 + i) * M_ + m0 + tx] = t[tx][i];
}

// ---------------------------------------------------------------------------
// K1: encoder approx GEMM via MFMA bf16, single term (K=128, 4 BK=32 steps).
// Epilogue: padded-LDS re-tile -> coalesced 16B stores to the HIGH half.
// ---------------------------------------------------------------------------
__device__ __forceinline__ int swz(int row) { return (row & 3) ^ ((row >> 2) & 3); }

#define CP 136   // C-tile row pitch in shorts

__global__ __launch_bounds__(256) void encoder_mfma(const unsigned short* __restrict__ Abf,
                                                    const unsigned short* __restrict__ Wbf,
                                                    const float* __restrict__ cvec,
                                                    unsigned short* __restrict__ y16) {
    const int l   = blockIdx.z;
    const int bn0 = blockIdx.x * 128;
    const int bm0 = blockIdx.y * 128;
    __shared__ __align__(16) unsigned short smem[128 * CP];   // 34.8KB
    unsigned short* As = smem;
    unsigned short* Bs = smem + 128 * 32;
    const int tid  = threadIdx.x;
    const int lane = tid & 63, wave = tid >> 6;
    const int wr = wave >> 1, wc = wave & 1;

    const unsigned short* Ab = Abf + (((size_t)l * B_ + bm0) << 7);
    const unsigned short* Wb = Wbf + (((size_t)l * N_ + bn0) << 7);

    auto stage = [&](int k0) {
        #pragma unroll
        for (int i = 0; i < 2; ++i) {
            int p   = i * 256 + tid;
            int row = p >> 2;
            int lc  = (p & 3) ^ swz(row);
            const unsigned short* g = Ab + ((size_t)row << 7) + k0 + lc * 8;
            unsigned dst = (unsigned)((i * 256 + (tid & ~63)) * 16);
            __builtin_amdgcn_global_load_lds(
                (const __attribute__((address_space(1))) void*)g,
                (__attribute__((address_space(3))) void*)((char*)As + dst), 16, 0, 0);
        }
        #pragma unroll
        for (int i = 0; i < 2; ++i) {
            int p   = i * 256 + tid;
            int row = p >> 2;
            int lc  = (p & 3) ^ swz(row);
            const unsigned short* g = Wb + ((size_t)row << 7) + k0 + lc * 8;
            unsigned dst = (unsigned)((i * 256 + (tid & ~63)) * 16);
            __builtin_amdgcn_global_load_lds(
                (const __attribute__((address_space(1))) void*)g,
                (__attribute__((address_space(3))) void*)((char*)Bs + dst), 16, 0, 0);
        }
    };

    f32x4 acc[4][4];
    #pragma unroll
    for (int i = 0; i < 4; ++i)
        #pragma unroll
        for (int j = 0; j < 4; ++j) acc[i][j] = (f32x4){0.f, 0.f, 0.f, 0.f};

    stage(0);
    __syncthreads();

    #pragma unroll
    for (int t = 0; t < 4; ++t) {
        short8_t aF[4], bF[4];
        const int kg = lane >> 4;
        #pragma unroll
        for (int mt = 0; mt < 4; ++mt) {
            int row = wr * 64 + mt * 16 + (lane & 15);
            int pc  = kg ^ swz(row);
            aF[mt] = *reinterpret_cast<const short8_t*>(As + row * 32 + pc * 8);
        }
        #pragma unroll
        for (int nt = 0; nt < 4; ++nt) {
            int row = wc * 64 + nt * 16 + (lane & 15);
            int pc  = kg ^ swz(row);
            bF[nt] = *reinterpret_cast<const short8_t*>(Bs + row * 32 + pc * 8);
        }
        #pragma unroll
        for (int mt = 0; mt < 4; ++mt)
            #pragma unroll
            for (int nt = 0; nt < 4; ++nt)
                acc[mt][nt] = __builtin_amdgcn_mfma_f32_16x16x32_bf16(
                    aF[mt], bF[nt], acc[mt][nt], 0, 0, 0);

        if (t < 3) {
            __syncthreads();
            stage((t + 1) * 32);
            __syncthreads();
        }
    }

    __syncthreads();   // staging dead; repurpose LDS as C tile

    #pragma unroll
    for (int nt = 0; nt < 4; ++nt) {
        int nl = wc * 64 + nt * 16 + (lane & 15);
        float cj = cvec[(size_t)l * N_ + bn0 + nl];
        #pragma unroll
        for (int mt = 0; mt < 4; ++mt) {
            #pragma unroll
            for (int j = 0; j < 4; ++j) {
                int rl = wr * 64 + mt * 16 + (lane >> 4) * 4 + j;
                smem[rl * CP + nl] = f2bf(acc[mt][nt][j] - cj);
            }
        }
    }
    __syncthreads();

    #pragma unroll
    for (int i = 0; i < 8; ++i) {
        int chunk = i * 256 + tid;
        int r = chunk >> 4, cch = chunk & 15;
        ushort8_t v = *reinterpret_cast<const ushort8_t*>(smem + r * CP + cch * 8);
        unsigned short* dst = y16 + ((size_t)((bm0 + r) * L_ + l)) * 8192 + 4096 + bn0 + cch * 8;
        *reinterpret_cast<ushort8_t*>(dst) = v;
    }
}

// ---------------------------------------------------------------------------
// K2 (wave-per-row selector+decoder, zero block barriers) == round 15:
// seeded bisect, ballot/scan pool, r4-verbatim exact recompute, exact rank,
// direct low-half scatter, fused decode (unroll 8 for deeper MLP).
// ---------------------------------------------------------------------------
#define POOL 96
#define MARGIN 1.2e-3f

__global__ __launch_bounds__(256) void topk_decode(float* __restrict__ y,
                                                   const float* __restrict__ We,
                                                   const float* __restrict__ WdT,
                                                   const float* __restrict__ kin,
                                                   const float* __restrict__ cvec,
                                                   int* __restrict__ cidx,
                                                   float* __restrict__ cval,
                                                   float* __restrict__ khat,
                                                   float* __restrict__ partial) {
    const int w    = threadIdx.x >> 6;          // wave id in block (0..3)
    const int lane = threadIdx.x & 63;
    const int wid  = (blockIdx.x << 2) + w;     // 0..32767, l-major
    const int l = wid >> 10, b = wid & 1023;
    const int row = b * L_ + l;

    __shared__ __align__(16) float kinS[4][M_];
    __shared__ int   pidxS[4][POOL];
    __shared__ float pexS[4][POOL];
    __shared__ int   sidxS[4][S_];
    __shared__ float svalS[4][S_];

    float* yo = y + (size_t)row * N_;
    const unsigned short* ya = (const unsigned short*)y + (size_t)row * 8192 + 4096;

    kinS[w][lane]      = kin[(size_t)row * M_ + lane];
    kinS[w][lane + 64] = kin[(size_t)row * M_ + lane + 64];

    // load 64 approx values (8 x 16B, coalesced)
    ushort8_t u[8];
    #pragma unroll
    for (int j = 0; j < 8; ++j)
        u[j] = *reinterpret_cast<const ushort8_t*>(ya + j * 512 + lane * 8);
    float a[64];
    #pragma unroll
    for (int j = 0; j < 8; ++j)
        #pragma unroll
        for (int e = 0; e < 8; ++e)
            a[j * 8 + e] = fabsf(bf2f(u[j][e]));

    // wave max + moments (for bisect seeding)
    float mx = 0.0f, s1 = 0.0f, s2 = 0.0f;
    #pragma unroll
    for (int i = 0; i < 64; ++i) {
        mx = fmaxf(mx, a[i]);
        s1 += a[i];
        s2 = fmaf(a[i], a[i], s2);
    }
    #pragma unroll
    for (int o = 32; o > 0; o >>= 1) {
        mx = fmaxf(mx, __shfl_xor(mx, o, 64));
        s1 += __shfl_xor(s1, o, 64);
        s2 += __shfl_xor(s2, o, 64);
    }
    const float mu  = s1 * (1.0f / 4096.0f);
    const float var = fmaxf(s2 * (1.0f / 4096.0f) - mu * mu, 0.0f);
    const float sg  = sqrtf(var);

    // bisect: invariant count(a >= lo) >= 32; tighten until count <= 40.
    float lo = 0.0f, hi = mx;
    int cl = N_;
    for (int it = 0; it < 30 && cl > 40; ++it) {
        float t;
        if      (it == 0) t = mu + 2.20f * sg;
        else if (it == 1) t = mu + 2.96f * sg;
        else              t = 0.5f * (lo + hi);
        t = fminf(fmaxf(t, lo), hi);
        int c = 0;
        #pragma unroll
        for (int i = 0; i < 64; ++i) c += (a[i] >= t) ? 1 : 0;
        #pragma unroll
        for (int o = 32; o > 0; o >>= 1) c += __shfl_xor(c, o, 64);
        if (c >= S_) { lo = t; cl = c; } else { hi = t; }
    }

    // pool via ballot/scan compaction (no atomics)
    const float th = lo - MARGIN;
    int myc = 0;
    #pragma unroll
    for (int i = 0; i < 64; ++i) myc += (a[i] >= th) ? 1 : 0;
    int pos = myc;
    #pragma unroll
    for (int o = 1; o < 64; o <<= 1) {
        int t = __shfl_up(pos, o, 64);
        if (lane >= o) pos += t;
    }
    const int base  = pos - myc;                // exclusive prefix
    const int total = __shfl(pos, 63, 64);
    int k = 0;
    #pragma unroll
    for (int j = 0; j < 8; ++j)
        #pragma unroll
        for (int e = 0; e < 8; ++e)
            if (a[j * 8 + e] >= th) {
                int p = base + k;
                if (p < POOL) pidxS[w][p] = j * 512 + lane * 8 + e;
                ++k;
            }
    __asm__ __volatile__("s_waitcnt lgkmcnt(0)" ::: "memory");
    int c = total < POOL ? total : POOL;

    // exact recompute: STRICT ascending-m fmaf chain (bit-identical to r4);
    // float4 loads (We global L2-hot, kin LDS) then 4 in-order scalar fmafs.
    if (lane < c) {
        int n = pidxS[w][lane];
        const float4* wp4 = reinterpret_cast<const float4*>(We + ((size_t)l * N_ + n) * M_);
        const float4* kp4 = reinterpret_cast<const float4*>(kinS[w]);
        float acc = -cvec[(size_t)l * N_ + n];
        #pragma unroll 8
        for (int m4 = 0; m4 < 32; ++m4) {
            float4 wv = wp4[m4], kv = kp4[m4];
            acc = fmaf(wv.x, kv.x, acc);
            acc = fmaf(wv.y, kv.y, acc);
            acc = fmaf(wv.z, kv.z, acc);
            acc = fmaf(wv.w, kv.w, acc);
        }
        pexS[w][lane] = acc;
    }
    if (lane + 64 < c) {
        int n = pidxS[w][lane + 64];
        const float4* wp4 = reinterpret_cast<const float4*>(We + ((size_t)l * N_ + n) * M_);
        const float4* kp4 = reinterpret_cast<const float4*>(kinS[w]);
        float acc = -cvec[(size_t)l * N_ + n];
        #pragma unroll 8
        for (int m4 = 0; m4 < 32; ++m4) {
            float4 wv = wp4[m4], kv = kp4[m4];
            acc = fmaf(wv.x, kv.x, acc);
            acc = fmaf(wv.y, kv.y, acc);
            acc = fmaf(wv.z, kv.z, acc);
            acc = fmaf(wv.w, kv.w, acc);
        }
        pexS[w][lane + 64] = acc;
    }
    __asm__ __volatile__("s_waitcnt lgkmcnt(0)" ::: "memory");

    // exact rank (lowest-index tie-break); winners into LDS lists
    for (int e = lane; e < c; e += 64) {
        float ae = fabsf(pexS[w][e]);
        int   ne = pidxS[w][e];
        int rank = 0;
        for (int j = 0; j < c; ++j) {
            float aj = fabsf(pexS[w][j]);
            rank += ((aj > ae) || (aj == ae && pidxS[w][j] < ne)) ? 1 : 0;
        }
        if (rank < S_) {
            sidxS[w][rank] = ne;
            svalS[w][rank] = pexS[w][e];
        }
    }
    __asm__ __volatile__("s_waitcnt lgkmcnt(0)" ::: "memory");

    // emit winner lists; DIRECT scatter of low-half winners
    if (lane < S_) {
        int n = sidxS[w][lane];
        float v = svalS[w][lane];
        cidx[(size_t)row * S_ + lane] = n;
        cval[(size_t)row * S_ + lane] = v;
        if (n < 2048) yo[n] = v;
    }

    // fused decode: 2 dims per lane; WdT rows L2-resident (l-major)
    const float* wt = WdT + (size_t)l * N_ * M_;
    float acc0 = 0.0f, acc1 = 0.0f;
    #pragma unroll 8
    for (int j = 0; j < S_; ++j) {
        float v = svalS[w][j];
        const float* wrp = wt + (size_t)sidxS[w][j] * M_;
        acc0 = fmaf(v, wrp[lane], acc0);
        acc1 = fmaf(v, wrp[lane + 64], acc1);
    }
    khat[(size_t)row * M_ + lane]      = acc0;
    khat[(size_t)row * M_ + lane + 64] = acc1;
    float r0 = acc0 - kinS[w][lane];
    float r1 = acc1 - kinS[w][lane + 64];
    float s = r0 * r0 + r1 * r1;
    #pragma unroll
    for (int o = 32; o > 0; o >>= 1) s += __shfl_xor(s, o, 64);
    if (lane == 0) partial[row] = s;
}

// ---------------------------------------------------------------------------
// K3: finish_high: zero the HIGH 8KB halves + scatter high winners, fused.
// 16 rows per block; block zeroes its rows, barrier (drains vmcnt), then
// scatters its own rows' n>=2048 winners. Block-local ordering suffices.
// ---------------------------------------------------------------------------
__global__ __launch_bounds__(256) void finish_high(float* __restrict__ y,
                                                   const int* __restrict__ cidx,
                                                   const float* __restrict__ cval) {
    const int bid = blockIdx.x;                 // 2048 blocks
    const int tid = threadIdx.x;
    const int row0 = bid * 16;
    const float4 z = {0.f, 0.f, 0.f, 0.f};
    #pragma unroll
    for (int i = 0; i < 32; ++i) {
        int g = i * 256 + tid;                  // 0..8191 float4s
        int r = row0 + (g >> 9);
        int slot = g & 511;
        reinterpret_cast<float4*>(y + (size_t)r * N_ + 2048)[slot] = z;
    }
    __syncthreads();    // compiler emits vmcnt(0) drain before barrier
    #pragma unroll
    for (int i = 0; i < 2; ++i) {
        int e = i * 256 + tid;                  // 0..511 winner entries
        int g = row0 * S_ + e;
        int n = cidx[g];
        if (n >= 2048) {
            int r = row0 + (e >> 5);
            y[(size_t)r * N_ + n] = cval[g];
        }
    }
}

// ---------------------------------------------------------------------------
// K4: deterministic reduction of 32768 partials -> loss (float4 loads)
// ---------------------------------------------------------------------------
__global__ __launch_bounds__(256) void reduce_loss(const float* __restrict__ partial,
                                                   float* __restrict__ out_loss) {
    __shared__ float red[256];
    int tid = threadIdx.x;
    float s = 0.0f;
    for (int i = tid; i < ROWS / 4; i += 256) {
        float4 v = reinterpret_cast<const float4*>(partial)[i];
        s += v.x + v.y + v.z + v.w;
    }
    red[tid] = s;
    __syncthreads();
    for (int off = 128; off > 0; off >>= 1) {
        if (tid < off) red[tid] += red[tid + off];
        __syncthreads();
    }
    if (tid == 0) out_loss[0] = red[0] / (float)((size_t)B_ * L_ * M_);
}

// ---------------------------------------------------------------------------
extern "C" void kernel_launch(void* const* d_in, const int* in_sizes, int n_in,
                              void* d_out, int out_size, void* d_ws, size_t ws_size,
                              hipStream_t stream) {
    const float* kin = (const float*)d_in[0];   // [B][L][M]
    const float* We  = (const float*)d_in[1];   // [L][N][M]
    // d_in[2] = b_e (unused by reference encode())
    const float* Wd  = (const float*)d_in[3];   // [L][M][N]
    const float* bd  = (const float*)d_in[4];   // [L][M]
    // d_in[5] = s (==32, hardcoded)

    float* out   = (float*)d_out;
    float* loss  = out;                                   // [1]
    float* khat  = out + 1;                               // [B*L*M]
    float* y_out = out + 1 + (size_t)B_ * L_ * M_;        // [B*L*N]

    // workspace layout. region0: Wbf (32MB). WdT either aliases region0
    // (small ws; transpose must run after encoder) or lives at +82MB
    // (big ws; transpose joins the prologue). Branch on ws_size is
    // deterministic across calls.
    char* ws = (char*)d_ws;
    unsigned short* Wbf = (unsigned short*)ws;                   // 32 MiB
    unsigned short* Abf = (unsigned short*)(ws + (64u << 20));   // 8 MiB
    int*   cidx    = (int*)  (ws + (72u << 20));                 // 4 MiB
    float* cval    = (float*)(ws + (76u << 20));                 // 4 MiB
    float* cvec    = (float*)(ws + (80u << 20));                 // 512 KiB
    float* partial = (float*)(ws + (81u << 20));                 // 128 KiB
    const bool wsBig = ws_size >= ((size_t)146u << 20);
    float* WdT = wsBig ? (float*)(ws + ((size_t)82u << 20))      // 64 MiB, no alias
                       : (float*)ws;                             // aliases Wbf

    // prologue: zero y low halves + prep_w + prep_a (+ transpose if wsBig)
    int nblocks = 26624 + (wsBig ? 16384 : 0);
    prologue<<<nblocks, 256, 0, stream>>>(y_out, We, bd, Wbf, cvec, kin, Abf, Wd, WdT);
    // encoder: approx bf16 into y high halves
    encoder_mfma<<<dim3(N_ / 128, B_ / 128, L_), 256, 0, stream>>>(
        Abf, Wbf, cvec, (unsigned short*)y_out);
    // fallback transpose (Wbf dead after encoder)
    if (!wsBig)
        transpose_wd<<<dim3(N_ / 32, M_ / 32, L_), 256, 0, stream>>>(Wd, WdT);
    // wave-per-row selector + decoder (direct low-half scatter)
    topk_decode<<<ROWS / 4, 256, 0, stream>>>(y_out, We, WdT, kin, cvec,
                                              cidx, cval, khat, partial);
    // zero high halves + scatter high winners (fused)
    finish_high<<<2048, 256, 0, stream>>>(y_out, cidx, cval);
    reduce_loss<<<1, 256, 0, stream>>>(partial, loss);
}